// Round 4
// baseline (45.623 us; speedup 1.0000x reference)
//
#include <hip/hip_runtime.h>

#define NN 16384
#define NT 512
#define PER 32
#define KWIN 4

__global__ __launch_bounds__(NT) void dag_eval_kernel(
    const int* __restrict__ left,
    const int* __restrict__ right,
    const unsigned char* __restrict__ reroll_raw,
    int* __restrict__ out)
{
    __shared__ __align__(16) unsigned char reach[NN];       // 0/1 bytes
    __shared__ __align__(16) unsigned char state[NN + 16];  // hs|hr<<1|final<<2; [NN..]=4
    __shared__ __align__(16) unsigned int  l16w[NN / 2];    // packed int16 children
    __shared__ __align__(16) unsigned int  r16w[NN / 2];
    __shared__ int flags[2];
    __shared__ int nzmask;
    __shared__ int cnt;

    const int tid = threadIdx.x;
    const int b0  = tid * PER;

    if (tid == 0) { nzmask = 0; cnt = 0; flags[0] = 0; flags[1] = 0; }
    if (tid < 16) state[NN + tid] = 4;

    // ---- children: coalesced int4 loads; pack to int16 (ids fit: 1..16383 / -16384..-1) ----
    unsigned int cpair[PER];   // per-node (left16) | (right16<<16), static-indexed only
    {
        const int4* l4 = (const int4*)left;
        const int4* r4 = (const int4*)right;
        #pragma unroll
        for (int j = 0; j < PER / 4; ++j) {
            int4 a = l4[(b0 >> 2) + j];
            int4 b = r4[(b0 >> 2) + j];
            cpair[4*j+0] = (a.x & 0xFFFF) | (b.x << 16);
            cpair[4*j+1] = (a.y & 0xFFFF) | (b.y << 16);
            cpair[4*j+2] = (a.z & 0xFFFF) | (b.z << 16);
            cpair[4*j+3] = (a.w & 0xFFFF) | (b.w << 16);
            l16w[(b0 >> 1) + 2*j    ] = (a.x & 0xFFFF) | (a.y << 16);
            l16w[(b0 >> 1) + 2*j + 1] = (a.z & 0xFFFF) | (a.w << 16);
            r16w[(b0 >> 1) + 2*j    ] = (b.x & 0xFFFF) | (b.y << 16);
            r16w[(b0 >> 1) + 2*j + 1] = (b.z & 0xFFFF) | (b.w << 16);
        }
    }

    // ---- leaf_is_reroll layout detection (first 16 KB safe for all layouts) ----
    {
        const uint4* rv4 = (const uint4*)reroll_raw;
        uint4 v0 = rv4[tid], v1 = rv4[tid + NT];
        unsigned int t = v0.x | v0.y | v0.z | v0.w | v1.x | v1.y | v1.z | v1.w;
        unsigned int m = 0;
        if (t & 0x000000FFu) m |= 1u;
        if (t & 0x0000FF00u) m |= 2u;
        if (t & 0x00FF0000u) m |= 4u;
        if (t & 0xFF000000u) m |= 8u;
        if (m) atomicOr(&nzmask, (int)m);
    }

    *(uint4*)&reach[b0]      = make_uint4(0u, 0u, 0u, 0u);
    *(uint4*)&reach[b0 + 16] = make_uint4(0u, 0u, 0u, 0u);
    if (tid == 0) reach[0] = 1;
    __syncthreads();

    const int mask   = nzmask;
    const int layout = ((mask & ~1) == 0) ? 0 : (((mask & 3) == 0) ? 1 : 2);
    const int*   ri = (const int*)reroll_raw;
    const float* rf = (const float*)reroll_raw;

    // ---- backward init: leaf contributions; final if both children leaves or saturated ----
    int sreg[PER];
    unsigned int todo = 0;
    #pragma unroll
    for (int k = 0; k < PER; ++k) {
        int c0 = (int)(short)(cpair[k] & 0xFFFF);
        int c1 = (int)(short)(cpair[k] >> 16);
        int s = 0;
        if (c0 < 0) {
            int id = -c0 - 1;
            bool rr = (layout == 2) ? (reroll_raw[id] != 0)
                     : (layout == 1) ? (rf[id] != 0.0f)
                                     : (ri[id] != 0);
            s |= rr ? 2 : 1;
        }
        if (c1 < 0) {
            int id = -c1 - 1;
            bool rr = (layout == 2) ? (reroll_raw[id] != 0)
                     : (layout == 1) ? (rf[id] != 0.0f)
                                     : (ri[id] != 0);
            s |= rr ? 2 : 1;
        }
        if ((c0 < 0 && c1 < 0) || s == 3) s |= 4;
        else todo |= 1u << k;
        sreg[k] = s;
        state[b0 + k] = (unsigned char)s;
    }
    __syncthreads();

    // ---- merged fixpoint: 2-level forward push + backward pull, 1 barrier/sweep ----
    unsigned int pushed = 0, mm = 0;
    for (int w = 0; ; ++w) {
        const int p = w & 1;
        bool ch = false;
        for (int it = 0; it < KWIN; ++it) {
            // forward: read own 32 reach bytes, movemask, push-once (2 levels)
            uint4 v0 = *(const uint4*)&reach[b0];
            uint4 v1 = *(const uint4*)&reach[b0 + 16];
            mm  =  ((v0.x * 0x01020408u) >> 24) & 0xFu;
            mm |= (((v0.y * 0x01020408u) >> 24) & 0xFu) << 4;
            mm |= (((v0.z * 0x01020408u) >> 24) & 0xFu) << 8;
            mm |= (((v0.w * 0x01020408u) >> 24) & 0xFu) << 12;
            mm |= (((v1.x * 0x01020408u) >> 24) & 0xFu) << 16;
            mm |= (((v1.y * 0x01020408u) >> 24) & 0xFu) << 20;
            mm |= (((v1.z * 0x01020408u) >> 24) & 0xFu) << 24;
            mm |= (((v1.w * 0x01020408u) >> 24) & 0xFu) << 28;
            unsigned int newp = mm & ~pushed;
            pushed |= newp;
            if (newp && !ch) { flags[p] = 1; ch = true; }
            while (newp) {
                int k = __builtin_ctz(newp);
                newp &= newp - 1u;
                int n = b0 + k;
                unsigned int wl = l16w[n >> 1], wr = r16w[n >> 1];
                int sh = (n & 1) * 16;
                int c0 = (int)(short)((wl >> sh) & 0xFFFF);
                int c1 = (int)(short)((wr >> sh) & 0xFFFF);
                if (c0 > 0) {
                    reach[c0] = (unsigned char)1;
                    unsigned int gl = l16w[c0 >> 1], gr = r16w[c0 >> 1];
                    int gs = (c0 & 1) * 16;
                    int g0 = (int)(short)((gl >> gs) & 0xFFFF);
                    int g1 = (int)(short)((gr >> gs) & 0xFFFF);
                    if (g0 > 0) reach[g0] = (unsigned char)1;
                    if (g1 > 0) reach[g1] = (unsigned char)1;
                }
                if (c1 > 0) {
                    reach[c1] = (unsigned char)1;
                    unsigned int gl = l16w[c1 >> 1], gr = r16w[c1 >> 1];
                    int gs = (c1 & 1) * 16;
                    int g0 = (int)(short)((gl >> gs) & 0xFFFF);
                    int g1 = (int)(short)((gr >> gs) & 0xFFFF);
                    if (g0 > 0) reach[g0] = (unsigned char)1;
                    if (g1 > 0) reach[g1] = (unsigned char)1;
                }
            }
            // backward: static-unrolled branchless-ish gather, finalize via bit2
            if (todo) {
                unsigned int t = todo;
                #pragma unroll
                for (int k = 0; k < PER; ++k) {
                    if ((t >> k) & 1u) {
                        int c0 = (int)(short)(cpair[k] & 0xFFFF);
                        int c1 = (int)(short)(cpair[k] >> 16);
                        int la = (c0 > 0) ? c0 : NN;
                        int ra = (c1 > 0) ? c1 : NN;
                        int sl = state[la];
                        int sr = state[ra];
                        int ns = sreg[k] | (sl & 3) | (sr & 3);
                        bool fin = ((sl & sr & 4) != 0) || ((ns & 3) == 3);
                        int ns2 = fin ? (ns | 4) : ns;
                        if (ns2 != sreg[k]) {
                            sreg[k] = ns2;
                            state[b0 + k] = (unsigned char)ns2;
                            if (!ch) { flags[p] = 1; ch = true; }
                        }
                        if (fin) todo &= ~(1u << k);
                    }
                }
            }
            __syncthreads();   // one barrier per sweep; last also publishes flags
        }
        int f = flags[p];
        if (tid == 0) flags[p ^ 1] = 0;
        __syncthreads();
        if (!f) break;
    }

    // ---- count: wave shuffle reduce, one atomic per wave ----
    int cc = __popc(mm);
    #pragma unroll
    for (int off = 32; off; off >>= 1) cc += __shfl_down(cc, off);
    if ((tid & 63) == 0) atomicAdd(&cnt, cc);

    // ---- outputs from registers, int4 stores ----
    int4* out4 = (int4*)out;
    #pragma unroll
    for (int j = 0; j < PER / 4; ++j) {
        int4 a, h, r;
        a.x = (mm >> (4*j+0)) & 1; a.y = (mm >> (4*j+1)) & 1;
        a.z = (mm >> (4*j+2)) & 1; a.w = (mm >> (4*j+3)) & 1;
        h.x =  sreg[4*j+0] & 1;       h.y =  sreg[4*j+1] & 1;
        h.z =  sreg[4*j+2] & 1;       h.w =  sreg[4*j+3] & 1;
        r.x = (sreg[4*j+0] >> 1) & 1; r.y = (sreg[4*j+1] >> 1) & 1;
        r.z = (sreg[4*j+2] >> 1) & 1; r.w = (sreg[4*j+3] >> 1) & 1;
        out4[(b0 >> 2) + j]            = a;
        out4[((NN + b0) >> 2) + j]     = h;
        out4[((2 * NN + b0) >> 2) + j] = r;
    }
    __syncthreads();
    if (tid == 0) out[3 * NN] = cnt;
}

extern "C" void kernel_launch(void* const* d_in, const int* in_sizes, int n_in,
                              void* d_out, int out_size, void* d_ws, size_t ws_size,
                              hipStream_t stream)
{
    const int* left  = (const int*)d_in[3];
    const int* right = (const int*)d_in[4];
    const unsigned char* reroll = (const unsigned char*)d_in[5];
    int* out = (int*)d_out;
    dag_eval_kernel<<<1, NT, 0, stream>>>(left, right, reroll, out);
}